// Round 7
// baseline (790.726 us; speedup 1.0000x reference)
//
#include <hip/hip_runtime.h>
#include <math.h>

// Problem constants (from reference): B=2048, P_ROWS=128, N=64, Q=8
#define NB    2048
#define PROWS 128
#define NDIM  64
#define QCNT  8

#define NQUAD (NB * QCNT)   // 16384 blocks: one per (b, q), 12KB stream each
#define NLIN  (NB * 2)      // 4096 blocks: one per (b, half of A1), 16KB each
#define CONTRIB 10          // 8 quad + 2 linear blocks per batch

// Fully fused single kernel (R6 two-kernel -> one):
//  - symmetric-P read (A,B,C 32x32 blocks; skip B^T) = 12KB/(b,q)  [R6, +31%]
//  - decoupled independent blocks                                  [R5, +10%]
//  - NEW: per-batch atomicMax(kappa) + completion counter; the 10th
//    contributor block for batch b computes beta and writes out[b] itself.
//    Removes the global kernel boundary (drain bubble + launch + finalize).
//  kappa >= 0 always (klin relu'd; kq >= 0 since quad >= (gv/sigma)^2),
//  so float atomicMax == uint atomicMax on the bit pattern, init 0.
// Norm trick: out = z0 + min(1/kraw,1)*v with kraw from raw v (||v|| cancels).
__global__ __launch_bounds__(256) void fused_kernel(
    const float* __restrict__ v,    // (B, 64)
    const float* __restrict__ A1,   // (B, 128, 64)
    const float* __restrict__ b1,   // (B, 128)
    const float* __restrict__ z0,   // (B, 64)
    const float* __restrict__ P,    // (B, 8, 64, 64)
    const float* __restrict__ qv,   // (B, 8, 64)
    const float* __restrict__ rr,   // (B, 8)
    unsigned int* __restrict__ kmax,  // (B) kappa max, uint bits, zeroed
    unsigned int* __restrict__ cnt,   // (B) completion counters, zeroed
    float* __restrict__ out)        // (B, 64)
{
    const int bid  = blockIdx.x;
    const int tid  = threadIdx.x;
    const int lane = tid & 63;
    const int w    = tid >> 6;

    __shared__ __align__(16) float s_v[NDIM];
    __shared__ __align__(16) float s_z[NDIM];
    __shared__ float s_red[4][4];
    __shared__ float s_lin[4];
    __shared__ float s_kblk;
    __shared__ int   s_done;
    __shared__ float s_beta;

    const int b = (bid < NQUAD) ? (bid >> 3) : ((bid - NQUAD) >> 1);

    if (tid < NDIM) {
        s_v[tid] = v[b * NDIM + tid];
        s_z[tid] = z0[b * NDIM + tid];
    }
    __syncthreads();

    if (bid < NQUAD) {
        // ================= QUAD ROLE: one (b, q) slice, 12KB =================
        const int qq = bid & 7;
        // thread = (row i = tid>>3 in [0,32), chunk j4 = tid&7)
        const int i  = tid >> 3;
        const int j4 = tid & 7;
        const float4 vu = *(const float4*)&s_v[j4 * 4];
        const float4 vl = *(const float4*)&s_v[32 + j4 * 4];
        const float4 zu = *(const float4*)&s_z[j4 * 4];
        const float4 zl = *(const float4*)&s_z[32 + j4 * 4];
        const float vi_u = s_v[i];
        const float vi_l = s_v[32 + i];
        const float zi_u = s_z[i];
        const float zi_l = s_z[32 + i];

        const float* Pq = P + ((size_t)b * QCNT + qq) * (NDIM * NDIM);
        // A: rows 0-31 cols 0-31; B: rows 0-31 cols 32-63; C: rows 32-63 cols 32-63
        const float4 pA = *(const float4*)&Pq[i * NDIM + j4 * 4];
        const float4 pB = *(const float4*)&Pq[i * NDIM + 32 + j4 * 4];
        const float4 pC = *(const float4*)&Pq[(32 + i) * NDIM + 32 + j4 * 4];

        const float dAv = pA.x * vu.x + pA.y * vu.y + pA.z * vu.z + pA.w * vu.w;
        const float dAz = pA.x * zu.x + pA.y * zu.y + pA.z * zu.z + pA.w * zu.w;
        const float dBv = pB.x * vl.x + pB.y * vl.y + pB.z * vl.z + pB.w * vl.w;
        const float dBz = pB.x * zl.x + pB.y * zl.y + pB.z * zl.z + pB.w * zl.w;
        const float dCv = pC.x * vl.x + pC.y * vl.y + pC.z * vl.z + pC.w * vl.w;
        const float dCz = pC.x * zl.x + pC.y * zl.y + pC.z * zl.z + pC.w * zl.w;

        float a0 = vi_u * dAv + 2.f * vi_u * dBv + vi_l * dCv;         // v'Pv
        float a1 = vi_u * dAz + vi_u * dBz + zi_u * dBv + vi_l * dCz;  // v'Pz0
        float a2 = zi_u * dAz + 2.f * zi_u * dBz + zi_l * dCz;         // z0'Pz0
        float a3 = 0.f;                                                // q.z0
        if (tid < 16) {  // 16 threads cover the q vector once
            const float4 q4 = *(const float4*)&qv[((size_t)b * QCNT + qq) * NDIM + tid * 4];
            const float4 vq = *(const float4*)&s_v[tid * 4];
            const float4 zq = *(const float4*)&s_z[tid * 4];
            a1 += q4.x * vq.x + q4.y * vq.y + q4.z * vq.z + q4.w * vq.w;  // + q.v
            a3  = q4.x * zq.x + q4.y * zq.y + q4.z * zq.z + q4.w * zq.w;
        }
        #pragma unroll
        for (int m = 32; m >= 1; m >>= 1) {
            a0 += __shfl_xor(a0, m);
            a1 += __shfl_xor(a1, m);
            a2 += __shfl_xor(a2, m);
            a3 += __shfl_xor(a3, m);
        }
        if (lane == 0) {
            s_red[w][0] = a0; s_red[w][1] = a1;
            s_red[w][2] = a2; s_red[w][3] = a3;
        }
        __syncthreads();
        if (tid == 0) {
            const float vPv = s_red[0][0] + s_red[1][0] + s_red[2][0] + s_red[3][0];
            const float gvw = s_red[0][1] + s_red[1][1] + s_red[2][1] + s_red[3][1];
            const float zPz = s_red[0][2] + s_red[1][2] + s_red[2][2] + s_red[3][2];
            const float qz  = s_red[0][3] + s_red[1][3] + s_red[2][3] + s_red[3][3];
            const float c0    = 0.5f * zPz + qz + rr[b * QCNT + qq];
            const float sigma = 2.f * c0;
            const float quad  = (gvw * gvw - 2.f * c0 * vPv) / (sigma * sigma);
            const float kq    = -gvw / sigma + sqrtf(quad);  // >= 0 (PSD)
            s_kblk = fmaxf(kq, 0.f);
        }
    } else {
        // ================= LINEAR ROLE: one (b, half of A1), 16KB =============
        const int half = (bid - NQUAD) & 1;
        const int sub = tid & 15;   // column chunk
        const int grp = tid >> 4;   // row group
        const float4 vB = *(const float4*)&s_v[sub * 4];
        const float4 zB = *(const float4*)&s_z[sub * 4];
        float lmax = -INFINITY;
        const float* A1b = A1 + (size_t)b * PROWS * NDIM;
        #pragma unroll
        for (int p = 0; p < 4; ++p) {
            const int row = half * 64 + p * 16 + grp;
            const float4 a = *(const float4*)&A1b[row * NDIM + sub * 4];
            float dv = a.x * vB.x + a.y * vB.y + a.z * vB.z + a.w * vB.w;
            float dz = a.x * zB.x + a.y * zB.y + a.z * zB.z + a.w * zB.w;
            #pragma unroll
            for (int m = 8; m >= 1; m >>= 1) {
                dv += __shfl_xor(dv, m);
                dz += __shfl_xor(dz, m);
            }
            if (sub == 0) {
                const float denom = b1[b * PROWS + row] - dz;  // > 0
                lmax = fmaxf(lmax, dv / denom);
            }
        }
        #pragma unroll
        for (int m = 32; m >= 1; m >>= 1) lmax = fmaxf(lmax, __shfl_xor(lmax, m));
        if (lane == 0) s_lin[w] = lmax;
        __syncthreads();
        if (tid == 0) {
            const float km = fmaxf(fmaxf(s_lin[0], s_lin[1]), fmaxf(s_lin[2], s_lin[3]));
            s_kblk = fmaxf(km, 0.f);  // relu
        }
    }

    // ================= COMMON EPILOGUE: fold kappa, maybe finish batch ========
    __syncthreads();
    if (tid == 0) {
        atomicMax(&kmax[b], __float_as_uint(s_kblk));  // non-neg float == uint order
        __threadfence();                                // release
        const unsigned old = atomicAdd(&cnt[b], 1u);
        s_done = (old == CONTRIB - 1);
        if (s_done) {
            __threadfence();                            // acquire
            const unsigned kb = atomicMax(&kmax[b], 0u);  // coherent RMW read
            const float kraw = __uint_as_float(kb);
            s_beta = fminf(1.f / kraw, 1.f);            // 1/0 = inf -> 1
        }
    }
    __syncthreads();
    if (s_done && tid < NDIM) {
        out[b * NDIM + tid] = s_z[tid] + s_beta * s_v[tid];
    }
}

extern "C" void kernel_launch(void* const* d_in, const int* in_sizes, int n_in,
                              void* d_out, int out_size, void* d_ws, size_t ws_size,
                              hipStream_t stream) {
    const float* v  = (const float*)d_in[0];
    const float* A1 = (const float*)d_in[1];
    const float* b1 = (const float*)d_in[2];
    const float* z0 = (const float*)d_in[3];
    const float* P  = (const float*)d_in[4];
    const float* qv = (const float*)d_in[5];
    const float* rr = (const float*)d_in[6];
    unsigned int* kmax = (unsigned int*)d_ws;        // NB uints
    unsigned int* cnt  = kmax + NB;                  // NB uints
    float* out = (float*)d_out;

    // zero kmax + counters each launch (deterministic across graph replays)
    hipMemsetAsync(d_ws, 0, 2 * NB * sizeof(unsigned int), stream);
    fused_kernel<<<NQUAD + NLIN, 256, 0, stream>>>(v, A1, b1, z0, P, qv, rr,
                                                   kmax, cnt, out);
}

// Round 8
// 65.473 us; speedup vs baseline: 12.0772x; 12.0772x over previous
//
#include <hip/hip_runtime.h>
#include <math.h>

// Problem constants (from reference): B=2048, P_ROWS=128, N=64, Q=8
#define NB    2048
#define PROWS 128
#define NDIM  64
#define QCNT  8

#define NQUAD (NB * QCNT)   // 16384 blocks: one per (b, q), 12KB stream each
#define NLIN  (NB * 2)      // 4096 blocks: one per (b, half of A1), 16KB each
#define CONTRIB 10          // 8 quad + 2 linear blocks per batch

// Fused single kernel, FENCE-FREE epilogue (R7's __threadfence() lowered to
// L2-writeback ops; 41K of them serialized the whole device -> 790us).
// All cross-block comms are device-scope atomics (coherent at L2 home, no
// cache maintenance needed). Ordering "my kmax-max durable before my cnt-add"
// is enforced by a register data dependency on the atomicMax return value
// (opaque asm), which forces s_waitcnt on the max's ack before the add issues.
// Reader side: the 10th finisher's atomicAdd RMW returning 9 implies all adds
// durable -> all maxes durable -> atomicMax(&kmax,0) RMW reads the final kappa.
//
//  - symmetric-P read (A,B,C 32x32 blocks; skip B^T) = 12KB/(b,q)  [R6, +31%]
//  - decoupled independent blocks                                  [R5, +10%]
//  - per-batch finisher writes out[b] directly (no finalize kernel boundary)
//  kappa >= 0 always (klin relu'd; kq >= 0 since quad >= (gv/sigma)^2),
//  so float max == uint max on bit patterns, init 0.
// Norm trick: out = z0 + min(1/kraw,1)*v with kraw from raw v (||v|| cancels).
__global__ __launch_bounds__(256) void fused_kernel(
    const float* __restrict__ v,    // (B, 64)
    const float* __restrict__ A1,   // (B, 128, 64)
    const float* __restrict__ b1,   // (B, 128)
    const float* __restrict__ z0,   // (B, 64)
    const float* __restrict__ P,    // (B, 8, 64, 64)
    const float* __restrict__ qv,   // (B, 8, 64)
    const float* __restrict__ rr,   // (B, 8)
    unsigned int* __restrict__ kmax,  // (B) kappa max, uint bits, zeroed
    unsigned int* __restrict__ cnt,   // (B) completion counters, zeroed
    float* __restrict__ out)        // (B, 64)
{
    const int bid  = blockIdx.x;
    const int tid  = threadIdx.x;
    const int lane = tid & 63;
    const int w    = tid >> 6;

    __shared__ __align__(16) float s_v[NDIM];
    __shared__ __align__(16) float s_z[NDIM];
    __shared__ float s_red[4][4];
    __shared__ float s_lin[4];
    __shared__ float s_kblk;
    __shared__ int   s_done;
    __shared__ float s_beta;

    const int b = (bid < NQUAD) ? (bid >> 3) : ((bid - NQUAD) >> 1);

    if (tid < NDIM) {
        s_v[tid] = v[b * NDIM + tid];
        s_z[tid] = z0[b * NDIM + tid];
    }
    __syncthreads();

    if (bid < NQUAD) {
        // ================= QUAD ROLE: one (b, q) slice, 12KB =================
        const int qq = bid & 7;
        // thread = (row i = tid>>3 in [0,32), chunk j4 = tid&7)
        const int i  = tid >> 3;
        const int j4 = tid & 7;
        const float4 vu = *(const float4*)&s_v[j4 * 4];
        const float4 vl = *(const float4*)&s_v[32 + j4 * 4];
        const float4 zu = *(const float4*)&s_z[j4 * 4];
        const float4 zl = *(const float4*)&s_z[32 + j4 * 4];
        const float vi_u = s_v[i];
        const float vi_l = s_v[32 + i];
        const float zi_u = s_z[i];
        const float zi_l = s_z[32 + i];

        const float* Pq = P + ((size_t)b * QCNT + qq) * (NDIM * NDIM);
        // A: rows 0-31 cols 0-31; B: rows 0-31 cols 32-63; C: rows 32-63 cols 32-63
        const float4 pA = *(const float4*)&Pq[i * NDIM + j4 * 4];
        const float4 pB = *(const float4*)&Pq[i * NDIM + 32 + j4 * 4];
        const float4 pC = *(const float4*)&Pq[(32 + i) * NDIM + 32 + j4 * 4];

        const float dAv = pA.x * vu.x + pA.y * vu.y + pA.z * vu.z + pA.w * vu.w;
        const float dAz = pA.x * zu.x + pA.y * zu.y + pA.z * zu.z + pA.w * zu.w;
        const float dBv = pB.x * vl.x + pB.y * vl.y + pB.z * vl.z + pB.w * vl.w;
        const float dBz = pB.x * zl.x + pB.y * zl.y + pB.z * zl.z + pB.w * zl.w;
        const float dCv = pC.x * vl.x + pC.y * vl.y + pC.z * vl.z + pC.w * vl.w;
        const float dCz = pC.x * zl.x + pC.y * zl.y + pC.z * zl.z + pC.w * zl.w;

        float a0 = vi_u * dAv + 2.f * vi_u * dBv + vi_l * dCv;         // v'Pv
        float a1 = vi_u * dAz + vi_u * dBz + zi_u * dBv + vi_l * dCz;  // v'Pz0
        float a2 = zi_u * dAz + 2.f * zi_u * dBz + zi_l * dCz;         // z0'Pz0
        float a3 = 0.f;                                                // q.z0
        if (tid < 16) {  // 16 threads cover the q vector once
            const float4 q4 = *(const float4*)&qv[((size_t)b * QCNT + qq) * NDIM + tid * 4];
            const float4 vq = *(const float4*)&s_v[tid * 4];
            const float4 zq = *(const float4*)&s_z[tid * 4];
            a1 += q4.x * vq.x + q4.y * vq.y + q4.z * vq.z + q4.w * vq.w;  // + q.v
            a3  = q4.x * zq.x + q4.y * zq.y + q4.z * zq.z + q4.w * zq.w;
        }
        #pragma unroll
        for (int m = 32; m >= 1; m >>= 1) {
            a0 += __shfl_xor(a0, m);
            a1 += __shfl_xor(a1, m);
            a2 += __shfl_xor(a2, m);
            a3 += __shfl_xor(a3, m);
        }
        if (lane == 0) {
            s_red[w][0] = a0; s_red[w][1] = a1;
            s_red[w][2] = a2; s_red[w][3] = a3;
        }
        __syncthreads();
        if (tid == 0) {
            const float vPv = s_red[0][0] + s_red[1][0] + s_red[2][0] + s_red[3][0];
            const float gvw = s_red[0][1] + s_red[1][1] + s_red[2][1] + s_red[3][1];
            const float zPz = s_red[0][2] + s_red[1][2] + s_red[2][2] + s_red[3][2];
            const float qz  = s_red[0][3] + s_red[1][3] + s_red[2][3] + s_red[3][3];
            const float c0    = 0.5f * zPz + qz + rr[b * QCNT + qq];
            const float sigma = 2.f * c0;
            const float quad  = (gvw * gvw - 2.f * c0 * vPv) / (sigma * sigma);
            const float kq    = -gvw / sigma + sqrtf(quad);  // >= 0 (PSD)
            s_kblk = fmaxf(kq, 0.f);
        }
    } else {
        // ================= LINEAR ROLE: one (b, half of A1), 16KB =============
        const int half = (bid - NQUAD) & 1;
        const int sub = tid & 15;   // column chunk
        const int grp = tid >> 4;   // row group
        const float4 vB = *(const float4*)&s_v[sub * 4];
        const float4 zB = *(const float4*)&s_z[sub * 4];
        float lmax = -INFINITY;
        const float* A1b = A1 + (size_t)b * PROWS * NDIM;
        #pragma unroll
        for (int p = 0; p < 4; ++p) {
            const int row = half * 64 + p * 16 + grp;
            const float4 a = *(const float4*)&A1b[row * NDIM + sub * 4];
            float dv = a.x * vB.x + a.y * vB.y + a.z * vB.z + a.w * vB.w;
            float dz = a.x * zB.x + a.y * zB.y + a.z * zB.z + a.w * zB.w;
            #pragma unroll
            for (int m = 8; m >= 1; m >>= 1) {
                dv += __shfl_xor(dv, m);
                dz += __shfl_xor(dz, m);
            }
            if (sub == 0) {
                const float denom = b1[b * PROWS + row] - dz;  // > 0
                lmax = fmaxf(lmax, dv / denom);
            }
        }
        #pragma unroll
        for (int m = 32; m >= 1; m >>= 1) lmax = fmaxf(lmax, __shfl_xor(lmax, m));
        if (lane == 0) s_lin[w] = lmax;
        __syncthreads();
        if (tid == 0) {
            const float km = fmaxf(fmaxf(s_lin[0], s_lin[1]), fmaxf(s_lin[2], s_lin[3]));
            s_kblk = fmaxf(km, 0.f);  // relu
        }
    }

    // ====== COMMON EPILOGUE: fence-free fold + last-finisher write ======
    __syncthreads();
    if (tid == 0) {
        unsigned int old = atomicMax(&kmax[b], __float_as_uint(s_kblk));
        // Opaque data dependency: the add's operand depends on the max's
        // returned value -> compiler must s_waitcnt the max's completion
        // (durable at coherent point) before issuing the add. No fence.
        unsigned int one = 1u;
        asm volatile("" : "+v"(one) : "v"(old));
        const unsigned int prev = atomicAdd(&cnt[b], one);
        const int done = (prev == CONTRIB - 1);
        s_done = done;
        if (done) {
            // RMW read at the coherent point sees all completed maxes.
            const unsigned int kb = atomicMax(&kmax[b], 0u);
            const float kraw = __uint_as_float(kb);
            s_beta = fminf(1.f / kraw, 1.f);   // 1/0 = inf -> 1 (alpha = ||v||)
        }
    }
    __syncthreads();
    if (s_done && tid < NDIM) {
        out[b * NDIM + tid] = s_z[tid] + s_beta * s_v[tid];
    }
}

extern "C" void kernel_launch(void* const* d_in, const int* in_sizes, int n_in,
                              void* d_out, int out_size, void* d_ws, size_t ws_size,
                              hipStream_t stream) {
    const float* v  = (const float*)d_in[0];
    const float* A1 = (const float*)d_in[1];
    const float* b1 = (const float*)d_in[2];
    const float* z0 = (const float*)d_in[3];
    const float* P  = (const float*)d_in[4];
    const float* qv = (const float*)d_in[5];
    const float* rr = (const float*)d_in[6];
    unsigned int* kmax = (unsigned int*)d_ws;        // NB uints
    unsigned int* cnt  = kmax + NB;                  // NB uints
    float* out = (float*)d_out;

    // zero kmax + counters each launch (deterministic across graph replays)
    hipMemsetAsync(d_ws, 0, 2 * NB * sizeof(unsigned int), stream);
    fused_kernel<<<NQUAD + NLIN, 256, 0, stream>>>(v, A1, b1, z0, P, qv, rr,
                                                   kmax, cnt, out);
}

// Round 10
// 51.190 us; speedup vs baseline: 15.4470x; 1.2790x over previous
//
#include <hip/hip_runtime.h>
#include <math.h>

// Problem constants (from reference): B=2048, P_ROWS=128, N=64, Q=8
#define NB    2048
#define PROWS 128
#define NDIM  64
#define QCNT  8

#define NQUAD (NB * QCNT)   // 16384 blocks: one per (b, q), 12KB stream each
#define NLIN  (NB * 2)      // 4096 blocks: one per (b, half of A1), 16KB each

// R10 = R9 with the nontemporal builtin fixed: __builtin_nontemporal_load
// requires a clang vector type (ext_vector_type), not HIP's float4 struct.
//  - R6 two-kernel epilogue (proven; atomic fusion in R7/R8 was slower)
//  - finer uniform partition (one block per (b,q) / per half-A1)
//  - nontemporal loads on the single-pass streams (P, A1, qv)
//  - symmetric-P read (A,B,C 32x32 blocks; skip B^T) = 12KB/(b,q)
// kappa >= 0 always (klin relu'd; kq >= 0 since quad >= (gv/sigma)^2).
// Norm trick: out = z0 + min(1/kraw,1)*v with kraw from raw v (||v|| cancels).

typedef float vf4 __attribute__((ext_vector_type(4)));

static __device__ __forceinline__ float4 ldnt4(const float* p) {
    vf4 t = __builtin_nontemporal_load((const vf4*)p);
    return make_float4(t.x, t.y, t.z, t.w);
}

__global__ __launch_bounds__(256) void main_kernel(
    const float* __restrict__ v,    // (B, 64)
    const float* __restrict__ A1,   // (B, 128, 64)
    const float* __restrict__ b1,   // (B, 128)
    const float* __restrict__ z0,   // (B, 64)
    const float* __restrict__ P,    // (B, 8, 64, 64)
    const float* __restrict__ qv,   // (B, 8, 64)
    const float* __restrict__ rr,   // (B, 8)
    float* __restrict__ ws)         // (B, 16) kappa slots
{
    const int bid  = blockIdx.x;
    const int tid  = threadIdx.x;
    const int lane = tid & 63;
    const int w    = tid >> 6;

    __shared__ __align__(16) float s_v[NDIM];
    __shared__ __align__(16) float s_z[NDIM];
    __shared__ float s_red[4][4];
    __shared__ float s_lin[4];

    const int b = (bid < NQUAD) ? (bid >> 3) : ((bid - NQUAD) >> 1);

    if (tid < NDIM) {
        s_v[tid] = v[b * NDIM + tid];    // reused by 10 blocks -> cached load
        s_z[tid] = z0[b * NDIM + tid];
    }
    __syncthreads();

    if (bid < NQUAD) {
        // ================= QUAD ROLE: one (b, q) slice, 12KB =================
        const int qq = bid & 7;
        // thread = (row i = tid>>3 in [0,32), chunk j4 = tid&7)
        const int i  = tid >> 3;
        const int j4 = tid & 7;
        const float4 vu = *(const float4*)&s_v[j4 * 4];
        const float4 vl = *(const float4*)&s_v[32 + j4 * 4];
        const float4 zu = *(const float4*)&s_z[j4 * 4];
        const float4 zl = *(const float4*)&s_z[32 + j4 * 4];
        const float vi_u = s_v[i];
        const float vi_l = s_v[32 + i];
        const float zi_u = s_z[i];
        const float zi_l = s_z[32 + i];

        const float* Pq = P + ((size_t)b * QCNT + qq) * (NDIM * NDIM);
        // A: rows 0-31 cols 0-31; B: rows 0-31 cols 32-63; C: rows 32-63 cols 32-63
        const float4 pA = ldnt4(&Pq[i * NDIM + j4 * 4]);
        const float4 pB = ldnt4(&Pq[i * NDIM + 32 + j4 * 4]);
        const float4 pC = ldnt4(&Pq[(32 + i) * NDIM + 32 + j4 * 4]);

        const float dAv = pA.x * vu.x + pA.y * vu.y + pA.z * vu.z + pA.w * vu.w;
        const float dAz = pA.x * zu.x + pA.y * zu.y + pA.z * zu.z + pA.w * zu.w;
        const float dBv = pB.x * vl.x + pB.y * vl.y + pB.z * vl.z + pB.w * vl.w;
        const float dBz = pB.x * zl.x + pB.y * zl.y + pB.z * zl.z + pB.w * zl.w;
        const float dCv = pC.x * vl.x + pC.y * vl.y + pC.z * vl.z + pC.w * vl.w;
        const float dCz = pC.x * zl.x + pC.y * zl.y + pC.z * zl.z + pC.w * zl.w;

        float a0 = vi_u * dAv + 2.f * vi_u * dBv + vi_l * dCv;         // v'Pv
        float a1 = vi_u * dAz + vi_u * dBz + zi_u * dBv + vi_l * dCz;  // v'Pz0
        float a2 = zi_u * dAz + 2.f * zi_u * dBz + zi_l * dCz;         // z0'Pz0
        float a3 = 0.f;                                                // q.z0
        if (tid < 16) {  // 16 threads cover the q vector once
            const float4 q4 = ldnt4(&qv[((size_t)b * QCNT + qq) * NDIM + tid * 4]);
            const float4 vq = *(const float4*)&s_v[tid * 4];
            const float4 zq = *(const float4*)&s_z[tid * 4];
            a1 += q4.x * vq.x + q4.y * vq.y + q4.z * vq.z + q4.w * vq.w;  // + q.v
            a3  = q4.x * zq.x + q4.y * zq.y + q4.z * zq.z + q4.w * zq.w;
        }
        #pragma unroll
        for (int m = 32; m >= 1; m >>= 1) {
            a0 += __shfl_xor(a0, m);
            a1 += __shfl_xor(a1, m);
            a2 += __shfl_xor(a2, m);
            a3 += __shfl_xor(a3, m);
        }
        if (lane == 0) {
            s_red[w][0] = a0; s_red[w][1] = a1;
            s_red[w][2] = a2; s_red[w][3] = a3;
        }
        __syncthreads();
        if (tid == 0) {
            const float vPv = s_red[0][0] + s_red[1][0] + s_red[2][0] + s_red[3][0];
            const float gvw = s_red[0][1] + s_red[1][1] + s_red[2][1] + s_red[3][1];
            const float zPz = s_red[0][2] + s_red[1][2] + s_red[2][2] + s_red[3][2];
            const float qz  = s_red[0][3] + s_red[1][3] + s_red[2][3] + s_red[3][3];
            const float c0    = 0.5f * zPz + qz + rr[b * QCNT + qq];
            const float sigma = 2.f * c0;
            const float quad  = (gvw * gvw - 2.f * c0 * vPv) / (sigma * sigma);
            const float kq    = -gvw / sigma + sqrtf(quad);  // >= 0 (PSD)
            ws[b * 16 + qq] = fmaxf(kq, 0.f);
        }
    } else {
        // ================= LINEAR ROLE: one (b, half of A1), 16KB =============
        const int half = (bid - NQUAD) & 1;
        const int sub = tid & 15;   // column chunk
        const int grp = tid >> 4;   // row group
        const float4 vB = *(const float4*)&s_v[sub * 4];
        const float4 zB = *(const float4*)&s_z[sub * 4];
        float lmax = -INFINITY;
        const float* A1b = A1 + (size_t)b * PROWS * NDIM;
        #pragma unroll
        for (int p = 0; p < 4; ++p) {
            const int row = half * 64 + p * 16 + grp;
            const float4 a = ldnt4(&A1b[row * NDIM + sub * 4]);
            float dv = a.x * vB.x + a.y * vB.y + a.z * vB.z + a.w * vB.w;
            float dz = a.x * zB.x + a.y * zB.y + a.z * zB.z + a.w * zB.w;
            #pragma unroll
            for (int m = 8; m >= 1; m >>= 1) {
                dv += __shfl_xor(dv, m);
                dz += __shfl_xor(dz, m);
            }
            if (sub == 0) {
                const float denom = b1[b * PROWS + row] - dz;  // > 0
                lmax = fmaxf(lmax, dv / denom);
            }
        }
        #pragma unroll
        for (int m = 32; m >= 1; m >>= 1) lmax = fmaxf(lmax, __shfl_xor(lmax, m));
        if (lane == 0) s_lin[w] = lmax;
        __syncthreads();
        if (tid == 0) {
            const float km = fmaxf(fmaxf(s_lin[0], s_lin[1]), fmaxf(s_lin[2], s_lin[3]));
            ws[b * 16 + 8 + half] = fmaxf(km, 0.f);  // relu
        }
    }
}

// out = z0 + min(1/kraw, 1) * v, kraw = max of 10 ws slots per batch.
__global__ __launch_bounds__(256) void finalize_kernel(
    const float* __restrict__ v,
    const float* __restrict__ z0,
    const float* __restrict__ ws,
    float* __restrict__ out)
{
    const int idx = blockIdx.x * 256 + threadIdx.x;  // over B*64
    const int b   = idx >> 6;
    const float* wb = ws + b * 16;
    float kraw = 0.f;
    #pragma unroll
    for (int s = 0; s < 10; ++s) kraw = fmaxf(kraw, wb[s]);
    const float beta = fminf(1.f / kraw, 1.f);  // 1/0 = inf -> 1
    out[idx] = z0[idx] + beta * v[idx];
}

extern "C" void kernel_launch(void* const* d_in, const int* in_sizes, int n_in,
                              void* d_out, int out_size, void* d_ws, size_t ws_size,
                              hipStream_t stream) {
    const float* v  = (const float*)d_in[0];
    const float* A1 = (const float*)d_in[1];
    const float* b1 = (const float*)d_in[2];
    const float* z0 = (const float*)d_in[3];
    const float* P  = (const float*)d_in[4];
    const float* qv = (const float*)d_in[5];
    const float* rr = (const float*)d_in[6];
    float* ws  = (float*)d_ws;   // B*16 floats = 128KB, all 10 live slots
                                 // written every launch before finalize reads
    float* out = (float*)d_out;

    main_kernel<<<NQUAD + NLIN, 256, 0, stream>>>(v, A1, b1, z0, P, qv, rr, ws);
    finalize_kernel<<<(NB * NDIM) / 256, 256, 0, stream>>>(v, z0, ws, out);
}